// Round 6
// baseline (666.470 us; speedup 1.0000x reference)
//
#include <hip/hip_runtime.h>
#include <hip/hip_bf16.h>
#include <math.h>

#define B_   16
#define S_   4096
#define DIN  1024
#define V_   512
#define FOUT 120

typedef __attribute__((ext_vector_type(8))) short bf16x8;
typedef __attribute__((ext_vector_type(4))) float f32x4;

__device__ const float CSCALE = 0.1f / (64.0f * 4096.0f);
__device__ const float EPSF = 1e-5f;

// fp32 -> bf16 RNE
__device__ inline unsigned short f2b(float f) {
  unsigned u = __builtin_bit_cast(unsigned, f);
  unsigned r = (u + 0x7FFFu + ((u >> 16) & 1u)) >> 16;
  return (unsigned short)r;
}

__device__ inline bf16x8 pack8(float4 a, float4 b) {
  bf16x8 r;
  r[0] = (short)f2b(a.x); r[1] = (short)f2b(a.y);
  r[2] = (short)f2b(a.z); r[3] = (short)f2b(a.w);
  r[4] = (short)f2b(b.x); r[5] = (short)f2b(b.y);
  r[6] = (short)f2b(b.z); r[7] = (short)f2b(b.w);
  return r;
}

// Wb[g][c][k] bf16, row-major (g in {q,k,v}, c=0..511, k=0..1023)
__global__ void msr_convw(const float* __restrict__ Wq, const float* __restrict__ Wk,
                          const float* __restrict__ Wv, unsigned short* __restrict__ Wb) {
  int u = blockIdx.x * 256 + threadIdx.x;   // 0..196607
  int g = u >> 16;
  const float* W = (g == 0) ? Wq : (g == 1) ? Wk : Wv;
  const float* src = W + (size_t)(u & 65535) * 8;
  float4 a = *(const float4*)src;
  float4 b = *(const float4*)(src + 4);
  *(bf16x8*)(Wb + (size_t)u * 8) = pack8(a, b);
}

// Xb = bf16(x), row-major [65536][1024]
__global__ __launch_bounds__(256) void msr_convx(const float* __restrict__ x,
                                                 unsigned short* __restrict__ Xb) {
  const size_t stride = (size_t)gridDim.x * 256;
  for (size_t i = blockIdx.x * 256ull + threadIdx.x; i < 8388608ull; i += stride) {
    const float* src = x + i * 8;
    float4 a = *(const float4*)src;
    float4 b = *(const float4*)(src + 4);
    *(bf16x8*)(Xb + i * 8) = pack8(a, b);
  }
}

// Main: NO LDS, NO BARRIERS. 512 thr = 8 waves, each wave fully independent.
// Block tile: M=128 x 128ch x 3g. Wave tile: M=64 (4 m-frags) x 32ch (2 n-frags) x 3g.
// A,B fragments loaded global->reg (bf16), 2-deep register double-buffer,
// fully unrolled K-loop (32 steps) => all loads are base+imm-offset.
// DIRECT=true: A from pre-converted Xb. DIRECT=false (ws fallback): fp32 + in-reg pack.
template <bool DIRECT>
__global__ __launch_bounds__(512, 2) void msr_main(
    const float* __restrict__ x, const unsigned short* __restrict__ Xb,
    const unsigned short* __restrict__ Wb, float* __restrict__ outacc) {
  const int bid = blockIdx.x;
  const int ct = bid & 3;          // one ct per XCD (bid%8 dispatch heuristic)
  const int rt = bid >> 2;         // 0..511
  const int r0 = rt << 7;

  const int t = threadIdx.x;
  const int w = t >> 6, lane = t & 63;
  const int wm = (w >> 2) * 64;    // M-half base
  const int cs = (w & 3) * 32;     // channel-slice base within ct-tile

  // Fragment mapping (HW-verified r2-r5): lane l -> index (l&15), k-octet (l>>4)*8
  const unsigned short* pB =
      Wb + (size_t)(ct * 128 + cs + (lane & 15)) * DIN + ((lane >> 4) << 3);
  const unsigned short* pA =
      Xb + (size_t)(r0 + wm + (lane & 15)) * DIN + ((lane >> 4) << 3);
  const float* pAf =
      x + (size_t)(r0 + wm + (lane & 15)) * DIN + ((lane >> 4) << 3);

  f32x4 acc[3][4][2];
#pragma unroll
  for (int g = 0; g < 3; ++g)
#pragma unroll
    for (int m = 0; m < 4; ++m)
#pragma unroll
      for (int n = 0; n < 2; ++n) acc[g][m][n] = (f32x4){0.f, 0.f, 0.f, 0.f};

  bf16x8 afr[2][4], bfr[2][3][2];

#define LOADSET(bb, kk) { \
  _Pragma("unroll") for (int m = 0; m < 4; ++m) { \
    if (DIRECT) { \
      afr[bb][m] = *(const bf16x8*)(pA + m * 16384 + (kk) * 32); \
    } else { \
      const float* p = pAf + m * 16384 + (kk) * 32; \
      afr[bb][m] = pack8(*(const float4*)p, *(const float4*)(p + 4)); \
    } \
  } \
  _Pragma("unroll") for (int g = 0; g < 3; ++g) \
  _Pragma("unroll") for (int n = 0; n < 2; ++n) \
    bfr[bb][g][n] = *(const bf16x8*)(pB + (size_t)g * 524288 + n * 16384 + (kk) * 32); }

  LOADSET(0, 0);
#pragma unroll
  for (int k = 0; k < 32; ++k) {
    if (k < 31) { LOADSET((k + 1) & 1, k + 1); }   // static after unroll
    const int c = k & 1;
    __builtin_amdgcn_s_setprio(1);
#pragma unroll
    for (int g = 0; g < 3; ++g)
#pragma unroll
      for (int m = 0; m < 4; ++m)
#pragma unroll
        for (int n = 0; n < 2; ++n)
          acc[g][m][n] = __builtin_amdgcn_mfma_f32_16x16x32_bf16(
              afr[c][m], bfr[c][g][n], acc[g][m][n], 0, 0, 0);
    __builtin_amdgcn_s_setprio(0);
  }
#undef LOADSET

  // Epilogue: p = (q*k)[c^1] * v[c]; fold rows; direct atomicAdd (no LDS).
  // C/D layout: col = lane&15 (channel), row = (lane>>4)*4 + r  [HW-verified]
  float pd0 = 0.f, pd1 = 0.f;
#pragma unroll
  for (int m = 0; m < 4; ++m)
#pragma unroll
    for (int r = 0; r < 4; ++r) {
      float qk0 = acc[0][m][0][r] * acc[1][m][0][r];
      float qk1 = acc[0][m][1][r] * acc[1][m][1][r];
      pd0 += __shfl_xor(qk0, 1, 64) * acc[2][m][0][r];
      pd1 += __shfl_xor(qk1, 1, 64) * acc[2][m][1][r];
    }
  pd0 += __shfl_xor(pd0, 16, 64); pd0 += __shfl_xor(pd0, 32, 64);
  pd1 += __shfl_xor(pd1, 16, 64); pd1 += __shfl_xor(pd1, 32, 64);

  // d = (ct*128 + cs + n*16 + (lane&15)) % 64 = (w&1)*32 + n*16 + (lane&15)
  if (lane < 16) {
    float* dst = &outacc[((rt >> 2) << 6) + (w & 1) * 32 + lane];
    atomicAdd(dst, pd0);
    atomicAdd(dst + 16, pd1);
  }
}

// Finish: per-batch RMSNorm -> exact gelu -> @ Wout.T
__global__ __launch_bounds__(256) void msr_finish(
    const float* __restrict__ outacc, const float* __restrict__ gamma,
    const float* __restrict__ Wout, float* __restrict__ y) {
  const int b = blockIdx.x;
  const int t = threadIdx.x;
  __shared__ float g[V_];
  __shared__ float wsum[4];

  float v0 = outacc[b * V_ + t] * CSCALE;
  float v1 = outacc[b * V_ + 256 + t] * CSCALE;
  float ss = v0 * v0 + v1 * v1;
#pragma unroll
  for (int o = 32; o > 0; o >>= 1) ss += __shfl_down(ss, o, 64);
  if ((t & 63) == 0) wsum[t >> 6] = ss;
  __syncthreads();
  float tot = wsum[0] + wsum[1] + wsum[2] + wsum[3];
  float rs = rsqrtf(tot * (1.0f / (float)V_) + EPSF);

  float r0v = v0 * rs * gamma[t];
  float r1v = v1 * rs * gamma[t + 256];
  g[t]       = 0.5f * r0v * (1.0f + erff(r0v * 0.70710678118654752f));
  g[t + 256] = 0.5f * r1v * (1.0f + erff(r1v * 0.70710678118654752f));
  __syncthreads();

  if (t < FOUT) {
    const float* wr = Wout + (size_t)t * V_;
    float acc = 0.f;
#pragma unroll 4
    for (int c = 0; c < V_; c += 4) {
      float4 w4 = *(const float4*)(wr + c);
      acc += g[c] * w4.x + g[c + 1] * w4.y + g[c + 2] * w4.z + g[c + 3] * w4.w;
    }
    y[b * FOUT + t] = acc;
  }
}

extern "C" void kernel_launch(void* const* d_in, const int* in_sizes, int n_in,
                              void* d_out, int out_size, void* d_ws, size_t ws_size,
                              hipStream_t stream) {
  const float* x     = (const float*)d_in[0];
  const float* Wq    = (const float*)d_in[1];
  const float* Wk    = (const float*)d_in[2];
  const float* Wv    = (const float*)d_in[3];
  const float* Wout  = (const float*)d_in[4];
  const float* gamma = (const float*)d_in[5];

  float* outacc = (float*)d_ws;                                    // 32 KB
  unsigned short* Wb = (unsigned short*)((char*)d_ws + 32768);     // 3 MB
  unsigned short* Xb = (unsigned short*)((char*)d_ws + 32768 + 3145728);  // 128 MB
  float* y = (float*)d_out;

  const size_t need = 32768ull + 3145728ull + 134217728ull;

  msr_convw<<<768, 256, 0, stream>>>(Wq, Wk, Wv, Wb);
  hipMemsetAsync(outacc, 0, B_ * V_ * sizeof(float), stream);

  if (ws_size >= need) {
    msr_convx<<<2048, 256, 0, stream>>>(x, Xb);
    msr_main<true><<<2048, 512, 0, stream>>>(x, Xb, Wb, outacc);
  } else {
    msr_main<false><<<2048, 512, 0, stream>>>(x, Xb, Wb, outacc);
  }
  msr_finish<<<B_, 256, 0, stream>>>(outacc, gamma, Wout, y);
}

// Round 7
// 337.317 us; speedup vs baseline: 1.9758x; 1.9758x over previous
//
#include <hip/hip_runtime.h>
#include <hip/hip_bf16.h>
#include <math.h>

#define B_   16
#define S_   4096
#define DIN  1024
#define V_   512
#define FOUT 120

typedef __attribute__((ext_vector_type(8))) short bf16x8;
typedef __attribute__((ext_vector_type(4))) float f32x4;

#define AS1 __attribute__((address_space(1)))
#define AS3 __attribute__((address_space(3)))

__device__ const float CSCALE = 0.1f / (64.0f * 4096.0f);
__device__ const float EPSF = 1e-5f;

__device__ inline void gl2lds16(const void* g, void* l) {
  __builtin_amdgcn_global_load_lds((const AS1 unsigned int*)g,
                                   (AS3 unsigned int*)l, 16, 0, 0);
}

// fp32 -> bf16 RNE
__device__ inline unsigned short f2b(float f) {
  unsigned u = __builtin_bit_cast(unsigned, f);
  unsigned r = (u + 0x7FFFu + ((u >> 16) & 1u)) >> 16;
  return (unsigned short)r;
}

__device__ inline bf16x8 pack8(float4 a, float4 b) {
  bf16x8 r;
  r[0] = (short)f2b(a.x); r[1] = (short)f2b(a.y);
  r[2] = (short)f2b(a.z); r[3] = (short)f2b(a.w);
  r[4] = (short)f2b(b.x); r[5] = (short)f2b(b.y);
  r[6] = (short)f2b(b.z); r[7] = (short)f2b(b.w);
  return r;
}

// Wt frag-major: e = ((ct*32 + k)*24 + f)*64 + l ; f = 3*nf + g (nf 0..7, g 0..2)
// lane l: channel ct*128 + nf*16 + (l&15), k = k*32 + (l>>4)*8 .. +8
__global__ void msr_convw(const float* __restrict__ Wq, const float* __restrict__ Wk,
                          const float* __restrict__ Wv, unsigned short* __restrict__ Wt) {
  int e = blockIdx.x * 256 + threadIdx.x;   // 0..196607
  int l = e & 63;
  int f = (e >> 6) % 24;
  int ck = (e >> 6) / 24;                   // ct*32 + k
  int k = ck & 31;
  int ct = ck >> 5;
  int nf = f / 3, g = f % 3;
  const float* W = (g == 0) ? Wq : (g == 1) ? Wk : Wv;
  int ch = ct * 128 + nf * 16 + (l & 15);
  const float* src = W + (size_t)ch * DIN + k * 32 + (l >> 4) * 8;
  float4 a = *(const float4*)src;
  float4 b = *(const float4*)(src + 4);
  *(bf16x8*)(Wt + (size_t)e * 8) = pack8(a, b);
}

// Xb = bf16(x), row-major [65536][1024] (r6-verified)
__global__ __launch_bounds__(256) void msr_convx(const float* __restrict__ x,
                                                 unsigned short* __restrict__ Xb) {
  const size_t stride = (size_t)gridDim.x * 256;
  for (size_t i = blockIdx.x * 256ull + threadIdx.x; i < 8388608ull; i += stride) {
    const float* src = x + i * 8;
    float4 a = *(const float4*)src;
    float4 b = *(const float4*)(src + 4);
    *(bf16x8*)(Xb + i * 8) = pack8(a, b);
  }
}

#define WAITVM3  asm volatile("s_waitcnt vmcnt(3)" ::: "memory")
#define WAITVM0  asm volatile("s_waitcnt vmcnt(0)" ::: "memory")
#define WAITLGKM asm volatile("s_waitcnt lgkmcnt(0)" ::: "memory")
#define SCHEDB   __builtin_amdgcn_sched_barrier(0)
#define BARRIER  { asm volatile("" ::: "memory"); __builtin_amdgcn_s_barrier(); asm volatile("" ::: "memory"); }

// Main: BM=128 rows x 128 ch (384 vcols = 3 GEMMs), BK=32, 32 K-steps.
// 8 waves (2M x 4N): wave tile 64 rows x 96 vcols -> acc[3][4][2] = 96 regs.
// 3-deep LDS pipeline (3 x 32KB): B via global_load_lds (counted vmcnt(3)),
// A via Xb->reg->ds_write (issue-early/write-late). Barriers never drain vmcnt.
template <bool DIRECT>
__global__ __launch_bounds__(512, 2) void msr_main(
    const float* __restrict__ x, const unsigned short* __restrict__ Xb,
    const unsigned short* __restrict__ Wt, float* __restrict__ outacc) {
  const int bid = blockIdx.x;
  const int ct = bid & 3;          // weight panel per ~XCD (L2-resident, 768KB)
  const int rt = bid >> 2;         // 0..511
  const int r0 = rt << 7;

  __shared__ __align__(16) unsigned char smem_[98304];   // 3 bufs x (A 8KB | B 24KB)

  const int t = threadIdx.x;
  const int w = t >> 6, lane = t & 63;
  const int wm4 = (w >> 2) * 4;               // m-frag base (0 or 4)
  const int l16 = lane * 16;
  const int w3 = w * 3;                       // B staging chunks w3..w3+2
  const size_t lane8 = (size_t)lane * 8;
  const int ctk = ct * 32;
  const int bread = 8192 + 6 * (w & 3) * 1024 + l16;  // B frag read base (bytes)

  // A loader: thread t -> row t>>2, octet t&3 ; frag-major LDS dest
  const int awoff = ((((t >> 2) >> 4) * 64) + (t & 3) * 16 + ((t >> 2) & 15)) * 16;
  const unsigned short* pXa = Xb + (size_t)(r0 + (t >> 2)) * DIN + (t & 3) * 8;
  const float* pXf = x + (size_t)(r0 + (t >> 2)) * DIN + (t & 3) * 8;

  f32x4 acc[3][4][2];
#pragma unroll
  for (int g = 0; g < 3; ++g)
#pragma unroll
    for (int m = 0; m < 4; ++m)
#pragma unroll
      for (int n = 0; n < 2; ++n) acc[g][m][n] = (f32x4){0.f, 0.f, 0.f, 0.f};

  bf16x8 afr[4], bfr[3], sa;

#define LOADA_(KK) (DIRECT ? *(const bf16x8*)(pXa + (size_t)(KK) * 32) \
    : pack8(*(const float4*)(pXf + (size_t)(KK) * 32), \
            *(const float4*)(pXf + (size_t)(KK) * 32 + 4)))

#define STAGEB_(KK, SB) { \
  _Pragma("unroll") for (int i = 0; i < 3; ++i) \
    gl2lds16(Wt + ((size_t)(ctk + (KK)) * 24 + w3 + i) * 512 + lane8, \
             smem_ + (SB) * 32768 + 8192 + (w3 + i) * 1024); }

#define STEP(KB, SB, KK, DOSTAGE, VMW) { \
  VMW; SCHEDB; \
  BARRIER; \
  _Pragma("unroll") for (int m = 0; m < 4; ++m) \
    afr[m] = *(const bf16x8*)(smem_ + (KB) * 32768 + (wm4 + m) * 1024 + l16); \
  _Pragma("unroll") for (int g = 0; g < 3; ++g) \
    bfr[g] = *(const bf16x8*)(smem_ + (KB) * 32768 + bread + g * 1024); \
  if (DOSTAGE) { sa = LOADA_((KK) + 2); SCHEDB; STAGEB_((KK) + 2, SB); } \
  WAITLGKM; SCHEDB; \
  __builtin_amdgcn_s_setprio(1); \
  _Pragma("unroll") for (int g = 0; g < 3; ++g) \
    _Pragma("unroll") for (int m = 0; m < 4; ++m) \
      acc[g][m][0] = __builtin_amdgcn_mfma_f32_16x16x32_bf16(afr[m], bfr[g], acc[g][m][0], 0, 0, 0); \
  __builtin_amdgcn_s_setprio(0); \
  BARRIER; \
  _Pragma("unroll") for (int g = 0; g < 3; ++g) \
    bfr[g] = *(const bf16x8*)(smem_ + (KB) * 32768 + bread + 3072 + g * 1024); \
  if (DOSTAGE) { *(bf16x8*)(smem_ + (SB) * 32768 + awoff) = sa; } \
  WAITLGKM; SCHEDB; \
  __builtin_amdgcn_s_setprio(1); \
  _Pragma("unroll") for (int g = 0; g < 3; ++g) \
    _Pragma("unroll") for (int m = 0; m < 4; ++m) \
      acc[g][m][1] = __builtin_amdgcn_mfma_f32_16x16x32_bf16(afr[m], bfr[g], acc[g][m][1], 0, 0, 0); \
  __builtin_amdgcn_s_setprio(0); \
}

  // ---- prologue: stage steps 0,1 into bufs 0,1 ----
  sa = LOADA_(0);
  *(bf16x8*)(smem_ + awoff) = sa;
  STAGEB_(0, 0);
  sa = LOADA_(1);
  *(bf16x8*)(smem_ + 32768 + awoff) = sa;
  STAGEB_(1, 1);
  WAITLGKM;

  // ---- main loop: steps 0..29 (staged), 30,31 (drain) ----
#pragma unroll 1
  for (int i = 0; i < 10; ++i) {
    const int k3 = i * 3;
    STEP(0, 2, k3,     1, WAITVM3);
    STEP(1, 0, k3 + 1, 1, WAITVM3);
    STEP(2, 1, k3 + 2, 1, WAITVM3);
  }
  STEP(0, 0, 30, 0, WAITVM3);
  STEP(1, 0, 31, 0, WAITVM0);
#undef STEP
#undef STAGEB_
#undef LOADA_

  // ---- epilogue: p = (q*k)[c^1] * v[c]; fold rows; direct atomicAdd [r5/r6-verified] ----
  float pd0 = 0.f, pd1 = 0.f;
#pragma unroll
  for (int m = 0; m < 4; ++m)
#pragma unroll
    for (int r = 0; r < 4; ++r) {
      float qk0 = acc[0][m][0][r] * acc[1][m][0][r];
      float qk1 = acc[0][m][1][r] * acc[1][m][1][r];
      pd0 += __shfl_xor(qk0, 1, 64) * acc[2][m][0][r];
      pd1 += __shfl_xor(qk1, 1, 64) * acc[2][m][1][r];
    }
  pd0 += __shfl_xor(pd0, 16, 64); pd0 += __shfl_xor(pd0, 32, 64);
  pd1 += __shfl_xor(pd1, 16, 64); pd1 += __shfl_xor(pd1, 32, 64);

  if (lane < 16) {
    float* dst = &outacc[((rt >> 2) << 6) + (w & 1) * 32 + lane];
    atomicAdd(dst, pd0);
    atomicAdd(dst + 16, pd1);
  }
}

// Finish: per-batch RMSNorm -> exact gelu -> @ Wout.T
__global__ __launch_bounds__(256) void msr_finish(
    const float* __restrict__ outacc, const float* __restrict__ gamma,
    const float* __restrict__ Wout, float* __restrict__ y) {
  const int b = blockIdx.x;
  const int t = threadIdx.x;
  __shared__ float g[V_];
  __shared__ float wsum[4];

  float v0 = outacc[b * V_ + t] * CSCALE;
  float v1 = outacc[b * V_ + 256 + t] * CSCALE;
  float ss = v0 * v0 + v1 * v1;
#pragma unroll
  for (int o = 32; o > 0; o >>= 1) ss += __shfl_down(ss, o, 64);
  if ((t & 63) == 0) wsum[t >> 6] = ss;
  __syncthreads();
  float tot = wsum[0] + wsum[1] + wsum[2] + wsum[3];
  float rs = rsqrtf(tot * (1.0f / (float)V_) + EPSF);

  float r0v = v0 * rs * gamma[t];
  float r1v = v1 * rs * gamma[t + 256];
  g[t]       = 0.5f * r0v * (1.0f + erff(r0v * 0.70710678118654752f));
  g[t + 256] = 0.5f * r1v * (1.0f + erff(r1v * 0.70710678118654752f));
  __syncthreads();

  if (t < FOUT) {
    const float* wr = Wout + (size_t)t * V_;
    float acc = 0.f;
#pragma unroll 4
    for (int c = 0; c < V_; c += 4) {
      float4 w4 = *(const float4*)(wr + c);
      acc += g[c] * w4.x + g[c + 1] * w4.y + g[c + 2] * w4.z + g[c + 3] * w4.w;
    }
    y[b * FOUT + t] = acc;
  }
}

extern "C" void kernel_launch(void* const* d_in, const int* in_sizes, int n_in,
                              void* d_out, int out_size, void* d_ws, size_t ws_size,
                              hipStream_t stream) {
  const float* x     = (const float*)d_in[0];
  const float* Wq    = (const float*)d_in[1];
  const float* Wk    = (const float*)d_in[2];
  const float* Wv    = (const float*)d_in[3];
  const float* Wout  = (const float*)d_in[4];
  const float* gamma = (const float*)d_in[5];

  float* outacc = (float*)d_ws;                                    // 32 KB
  unsigned short* Wt = (unsigned short*)((char*)d_ws + 32768);     // 3 MB
  unsigned short* Xb = (unsigned short*)((char*)d_ws + 32768 + 3145728);  // 128 MB
  float* y = (float*)d_out;

  const size_t need = 32768ull + 3145728ull + 134217728ull;

  msr_convw<<<768, 256, 0, stream>>>(Wq, Wk, Wv, Wt);
  hipMemsetAsync(outacc, 0, B_ * V_ * sizeof(float), stream);

  if (ws_size >= need) {
    msr_convx<<<2048, 256, 0, stream>>>(x, Xb);
    msr_main<true><<<2048, 512, 0, stream>>>(x, Xb, Wt, outacc);
  } else {
    msr_main<false><<<2048, 512, 0, stream>>>(x, Xb, Wt, outacc);
  }
  msr_finish<<<B_, 256, 0, stream>>>(outacc, gamma, Wout, y);
}

// Round 8
// 269.679 us; speedup vs baseline: 2.4713x; 1.2508x over previous
//
#include <hip/hip_runtime.h>
#include <hip/hip_bf16.h>
#include <math.h>

#define B_   16
#define S_   4096
#define DIN  1024
#define V_   512
#define FOUT 120

typedef __attribute__((ext_vector_type(8))) short bf16x8;
typedef __attribute__((ext_vector_type(4))) float f32x4;

#define AS1 __attribute__((address_space(1)))
#define AS3 __attribute__((address_space(3)))

__device__ const float CSCALE = 0.1f / (64.0f * 4096.0f);
__device__ const float EPSF = 1e-5f;

__device__ inline void gl2lds16(const void* g, void* l) {
  __builtin_amdgcn_global_load_lds((const AS1 unsigned int*)g,
                                   (AS3 unsigned int*)l, 16, 0, 0);
}

// fp32 -> bf16 RNE
__device__ inline unsigned short f2b(float f) {
  unsigned u = __builtin_bit_cast(unsigned, f);
  unsigned r = (u + 0x7FFFu + ((u >> 16) & 1u)) >> 16;
  return (unsigned short)r;
}

__device__ inline bf16x8 pack8(float4 a, float4 b) {
  bf16x8 r;
  r[0] = (short)f2b(a.x); r[1] = (short)f2b(a.y);
  r[2] = (short)f2b(a.z); r[3] = (short)f2b(a.w);
  r[4] = (short)f2b(b.x); r[5] = (short)f2b(b.y);
  r[6] = (short)f2b(b.z); r[7] = (short)f2b(b.w);
  return r;
}

// Wt frag-major (r7-verified): e = ((ct*32 + k)*24 + f)*64 + l ; f = 3*nf + g
// lane l: channel ct*128 + nf*16 + (l&15), k-elem k*32 + (l>>4)*8
__global__ void msr_convw(const float* __restrict__ Wq, const float* __restrict__ Wk,
                          const float* __restrict__ Wv, unsigned short* __restrict__ Wt) {
  int e = blockIdx.x * 256 + threadIdx.x;
  int l = e & 63;
  int f = (e >> 6) % 24;
  int ck = (e >> 6) / 24;
  int k = ck & 31;
  int ct = ck >> 5;
  int nf = f / 3, g = f % 3;
  const float* W = (g == 0) ? Wq : (g == 1) ? Wk : Wv;
  int ch = ct * 128 + nf * 16 + (l & 15);
  const float* src = W + (size_t)ch * DIN + k * 32 + (l >> 4) * 8;
  float4 a = *(const float4*)src;
  float4 b = *(const float4*)(src + 4);
  *(bf16x8*)(Wt + (size_t)e * 8) = pack8(a, b);
}

// Xb = bf16(x), row-major [65536][1024] (r6/r7-verified)
__global__ __launch_bounds__(256) void msr_convx(const float* __restrict__ x,
                                                 unsigned short* __restrict__ Xb) {
  const size_t stride = (size_t)gridDim.x * 256;
  for (size_t i = blockIdx.x * 256ull + threadIdx.x; i < 8388608ull; i += stride) {
    const float* src = x + i * 8;
    float4 a = *(const float4*)src;
    float4 b = *(const float4*)(src + 4);
    *(bf16x8*)(Xb + i * 8) = pack8(a, b);
  }
}

#define WAITVM4  asm volatile("s_waitcnt vmcnt(4)" ::: "memory")
#define WAITVM0  asm volatile("s_waitcnt vmcnt(0)" ::: "memory")
#define WAITLGKM asm volatile("s_waitcnt lgkmcnt(0)" ::: "memory")
#define SCHEDB   __builtin_amdgcn_sched_barrier(0)
#define BARRIER  { asm volatile("" ::: "memory"); __builtin_amdgcn_s_barrier(); asm volatile("" ::: "memory"); }

// Main: BM=128 x 128ch x 3g, BK=32, 32 steps. 8 waves (2M x 4N), acc[3][4][2]=96.
// 3-buf LDS (3 x 32KB). Per step: 10 ds_read (compiler-counted lgkm), 4 gl2lds
// (1 A via per-lane pre-swizzled source + 3 B), ONE vmcnt(4), ONE barrier.
template <bool DIRECT>
__global__ __launch_bounds__(512, 2) void msr_main(
    const float* __restrict__ x, const unsigned short* __restrict__ Xb,
    const unsigned short* __restrict__ Wt, float* __restrict__ outacc) {
  const int bid = blockIdx.x;
  const int ct = bid & 3;
  const int rt = bid >> 2;
  const int r0 = rt << 7;

  __shared__ __align__(16) unsigned char smem_[98304];   // 3 bufs x (A 8KB | B 24KB)

  const int t = threadIdx.x;
  const int w = t >> 6, lane = t & 63;
  const int wm4 = (w >> 2) * 4;
  const int l16 = lane * 16;
  const int w3 = w * 3;
  const int ctk = ct * 32;
  const int bread = 8192 + 6 * (w & 3) * 1024 + l16;

  // A stage: wave w owns m-frag w; per-lane global source (m173 pre-swizzle):
  // lane l -> row r0 + w*16 + (l&15), k-octet l>>4 ; dest = base + lane*16 (HW)
  const unsigned short* pXs = Xb + (size_t)(r0 + w * 16 + (lane & 15)) * DIN + ((lane >> 4) << 3);

  // fallback A loader (pack + ds_write), r7-verified mapping
  const int awoff = ((((t >> 2) >> 4) * 64) + (t & 3) * 16 + ((t >> 2) & 15)) * 16;
  const float* pXf = x + (size_t)(r0 + (t >> 2)) * DIN + (t & 3) * 8;

  f32x4 acc[3][4][2];
#pragma unroll
  for (int g = 0; g < 3; ++g)
#pragma unroll
    for (int m = 0; m < 4; ++m)
#pragma unroll
      for (int n = 0; n < 2; ++n) acc[g][m][n] = (f32x4){0.f, 0.f, 0.f, 0.f};

  bf16x8 afr[4], bfr0[3], bfr1[3];

#define STAGE(KK, SB) { \
  if (DIRECT) { \
    gl2lds16(pXs + (size_t)(KK) * 32, smem_ + (SB) * 32768 + w * 1024); \
  } else { \
    const float* p = pXf + (size_t)(KK) * 32; \
    *(bf16x8*)(smem_ + (SB) * 32768 + awoff) = pack8(*(const float4*)p, *(const float4*)(p + 4)); \
  } \
  _Pragma("unroll") for (int i = 0; i < 3; ++i) \
    gl2lds16(Wt + ((size_t)(ctk + (KK)) * 24 + w3 + i) * 512 + (size_t)lane * 8, \
             smem_ + (SB) * 32768 + 8192 + (w3 + i) * 1024); }

#define READS(KB) { \
  _Pragma("unroll") for (int m = 0; m < 4; ++m) \
    afr[m] = *(const bf16x8*)(smem_ + (KB) * 32768 + (wm4 + m) * 1024 + l16); \
  _Pragma("unroll") for (int g = 0; g < 3; ++g) \
    bfr0[g] = *(const bf16x8*)(smem_ + (KB) * 32768 + bread + g * 1024); \
  _Pragma("unroll") for (int g = 0; g < 3; ++g) \
    bfr1[g] = *(const bf16x8*)(smem_ + (KB) * 32768 + bread + 3072 + g * 1024); }

#define MFMAP(NN, BFR) { \
  __builtin_amdgcn_s_setprio(1); \
  _Pragma("unroll") for (int g = 0; g < 3; ++g) \
  _Pragma("unroll") for (int m = 0; m < 4; ++m) \
    acc[g][m][NN] = __builtin_amdgcn_mfma_f32_16x16x32_bf16(afr[m], BFR[g], acc[g][m][NN], 0, 0, 0); \
  __builtin_amdgcn_s_setprio(0); }

#define STEP(KB, SB, KK, DOSTAGE, VMW) { \
  READS(KB); \
  if (DOSTAGE) { STAGE((KK) + 2, SB); } \
  SCHEDB; \
  MFMAP(0, bfr0); \
  MFMAP(1, bfr1); \
  if (!DIRECT) { WAITLGKM; } \
  VMW; \
  BARRIER; }

  // ---- prologue: stage steps 0,1 into bufs 0,1 ----
  STAGE(0, 0);
  STAGE(1, 1);
  if (!DIRECT) { WAITLGKM; }
  WAITVM4;               // stage(0) landed (stage(1) = 4 newest still in flight)
  BARRIER;

  // ---- steps 0..29 ----
#pragma unroll 1
  for (int i = 0; i < 10; ++i) {
    const int k3 = i * 3;
    STEP(0, 2, k3,     1, WAITVM4);
    STEP(1, 0, k3 + 1, 1, WAITVM4);
    STEP(2, 1, k3 + 2, 1, WAITVM4);
  }
  // ---- step 30: no stage; drain stage(31) fully before last step ----
  STEP(0, 0, 30, 0, WAITVM0);
  // ---- step 31: compute only ----
  READS(1);
  MFMAP(0, bfr0);
  MFMAP(1, bfr1);
#undef STEP
#undef MFMAP
#undef READS
#undef STAGE

  // ---- epilogue (r5/r6/r7-verified): p = (q*k)[c^1]*v[c]; fold; atomicAdd ----
  float pd0 = 0.f, pd1 = 0.f;
#pragma unroll
  for (int m = 0; m < 4; ++m)
#pragma unroll
    for (int r = 0; r < 4; ++r) {
      float qk0 = acc[0][m][0][r] * acc[1][m][0][r];
      float qk1 = acc[0][m][1][r] * acc[1][m][1][r];
      pd0 += __shfl_xor(qk0, 1, 64) * acc[2][m][0][r];
      pd1 += __shfl_xor(qk1, 1, 64) * acc[2][m][1][r];
    }
  pd0 += __shfl_xor(pd0, 16, 64); pd0 += __shfl_xor(pd0, 32, 64);
  pd1 += __shfl_xor(pd1, 16, 64); pd1 += __shfl_xor(pd1, 32, 64);

  if (lane < 16) {
    float* dst = &outacc[((rt >> 2) << 6) + (w & 1) * 32 + lane];
    atomicAdd(dst, pd0);
    atomicAdd(dst + 16, pd1);
  }
}

// Finish: per-batch RMSNorm -> exact gelu -> @ Wout.T (verified r1-r7)
__global__ __launch_bounds__(256) void msr_finish(
    const float* __restrict__ outacc, const float* __restrict__ gamma,
    const float* __restrict__ Wout, float* __restrict__ y) {
  const int b = blockIdx.x;
  const int t = threadIdx.x;
  __shared__ float g[V_];
  __shared__ float wsum[4];

  float v0 = outacc[b * V_ + t] * CSCALE;
  float v1 = outacc[b * V_ + 256 + t] * CSCALE;
  float ss = v0 * v0 + v1 * v1;
#pragma unroll
  for (int o = 32; o > 0; o >>= 1) ss += __shfl_down(ss, o, 64);
  if ((t & 63) == 0) wsum[t >> 6] = ss;
  __syncthreads();
  float tot = wsum[0] + wsum[1] + wsum[2] + wsum[3];
  float rs = rsqrtf(tot * (1.0f / (float)V_) + EPSF);

  float r0v = v0 * rs * gamma[t];
  float r1v = v1 * rs * gamma[t + 256];
  g[t]       = 0.5f * r0v * (1.0f + erff(r0v * 0.70710678118654752f));
  g[t + 256] = 0.5f * r1v * (1.0f + erff(r1v * 0.70710678118654752f));
  __syncthreads();

  if (t < FOUT) {
    const float* wr = Wout + (size_t)t * V_;
    float acc = 0.f;
#pragma unroll 4
    for (int c = 0; c < V_; c += 4) {
      float4 w4 = *(const float4*)(wr + c);
      acc += g[c] * w4.x + g[c + 1] * w4.y + g[c + 2] * w4.z + g[c + 3] * w4.w;
    }
    y[b * FOUT + t] = acc;
  }
}

extern "C" void kernel_launch(void* const* d_in, const int* in_sizes, int n_in,
                              void* d_out, int out_size, void* d_ws, size_t ws_size,
                              hipStream_t stream) {
  const float* x     = (const float*)d_in[0];
  const float* Wq    = (const float*)d_in[1];
  const float* Wk    = (const float*)d_in[2];
  const float* Wv    = (const float*)d_in[3];
  const float* Wout  = (const float*)d_in[4];
  const float* gamma = (const float*)d_in[5];

  float* outacc = (float*)d_ws;                                    // 32 KB
  unsigned short* Wt = (unsigned short*)((char*)d_ws + 32768);     // 3 MB
  unsigned short* Xb = (unsigned short*)((char*)d_ws + 32768 + 3145728);  // 128 MB
  float* y = (float*)d_out;

  const size_t need = 32768ull + 3145728ull + 134217728ull;

  msr_convw<<<768, 256, 0, stream>>>(Wq, Wk, Wv, Wt);
  hipMemsetAsync(outacc, 0, B_ * V_ * sizeof(float), stream);

  if (ws_size >= need) {
    msr_convx<<<2048, 256, 0, stream>>>(x, Xb);
    msr_main<true><<<2048, 512, 0, stream>>>(x, Xb, Wt, outacc);
  } else {
    msr_main<false><<<2048, 512, 0, stream>>>(x, Xb, Wt, outacc);
  }
  msr_finish<<<B_, 256, 0, stream>>>(outacc, gamma, Wout, y);
}